// Round 9
// baseline (591.948 us; speedup 1.0000x reference)
//
#include <hip/hip_runtime.h>

#define NN 100000
#define NE 3200000
#define D 128
#define HD 64                         // half feature dim
#define ND (NN * D)
#define NDPH (NN * HD + HD)           // half-table elems: +1 zero row (sentinel)
#define KMAX 10
#define RPB 4                         // rows (waves) per block
#define RBLK ((NN + RPB - 1) / RPB)   // 25000
#define NEPAD (NE + 8 * NN + 128)     // >= sum of padded bucket regions + slack
#define SKIP_EPS 1e-3f                // remaining-contribution cutoff
#define NBUCK ((NN + 127) / 128)      // 782 row-buckets of 128 rows
#define CH 8192                       // edges per chunk (hist/bin blocks)
#define NCB ((NE + CH - 1) / CH)      // 391 chunk blocks

typedef float f32x4 __attribute__((ext_vector_type(4)));
typedef int i32x2 __attribute__((ext_vector_type(2)));
typedef unsigned u32x4 __attribute__((ext_vector_type(4)));

__device__ __forceinline__ float bflo(unsigned u) { return __uint_as_float(u << 16); }
__device__ __forceinline__ float bfhi(unsigned u) { return __uint_as_float(u & 0xffff0000u); }
__device__ __forceinline__ unsigned packbf(float lo, float hi) {
    unsigned bx = __float_as_uint(lo);
    bx = (bx + 0x7fffu + ((bx >> 16) & 1u)) >> 16;
    unsigned by = __float_as_uint(hi);
    by = (by + 0x7fffu + ((by >> 16) & 1u)) & 0xffff0000u;
    return by | bx;
}

// Per-chunk LDS histogram of bucket counts; flush with <=782 atomics/block.
__global__ __launch_bounds__(256) void hist_kernel(const int* __restrict__ row,
                                                   int* __restrict__ hist) {
    __shared__ int lh[NBUCK];
    int t = threadIdx.x;
    for (int b = t; b < NBUCK; b += 256) lh[b] = 0;
    __syncthreads();
    int e0 = blockIdx.x * CH;
    int n = NE - e0; if (n > CH) n = CH;
    for (int i = t; i < n; i += 256)
        atomicAdd(&lh[row[e0 + i] >> 7], 1);
    __syncthreads();
    int x = blockIdx.x & 7;
    for (int b = t; b < NBUCK; b += 256)
        if (lh[b]) atomicAdd(&hist[x * NBUCK + b], lh[b]);
}

// Single-block scans over buckets: bin layout (dense) + epk regions (padded
// upper bound total+896, rounded to 8). Also fused coefficient/truncation
// precompute (incl. last-live-k -> meta[0]) and the dis sentinel.
__global__ __launch_bounds__(1024) void scan_small_kernel(
    const int* __restrict__ hist, int* __restrict__ seg_off,
    int* __restrict__ cnt2, int* __restrict__ bbase, int* __restrict__ ebase,
    const float* __restrict__ alpha, const float* __restrict__ beta,
    const float* __restrict__ gamma, int* __restrict__ skipflag,
    float* __restrict__ fcoef, int* __restrict__ meta,
    float* __restrict__ dis) {
    __shared__ int sA[1024], sB[1024];
    int t = threadIdx.x;
    int tot = 0;
    int so[8];
    if (t < NBUCK) {
        int s = 0;
        for (int x = 0; x < 8; ++x) { so[x] = s; s += hist[x * NBUCK + t]; }
        tot = s;
    }
    int reg = (t < NBUCK) ? ((tot + 896 + 7) & ~7) : 0;
    sA[t] = tot; sB[t] = reg;
    __syncthreads();
    for (int off = 1; off < 1024; off <<= 1) {
        int a = (t >= off) ? sA[t - off] : 0;
        int c = (t >= off) ? sB[t - off] : 0;
        __syncthreads();
        sA[t] += a; sB[t] += c;
        __syncthreads();
    }
    if (t < NBUCK) {
        int ba = sA[t] - tot, eb = sB[t] - reg;
        bbase[t] = ba; ebase[t] = eb;
        for (int x = 0; x < 8; ++x) {
            seg_off[x * NBUCK + t] = ba + so[x];
            cnt2[x * NBUCK + t] = 0;
        }
    }
    if (t == 0) {
        bbase[NBUCK] = sA[1023];
        ebase[NBUCK] = sB[1023];
        dis[NN] = 0.0f;                    // sentinel weight
        float g[KMAX];
        for (int i = 0; i < KMAX; ++i) g[i] = gamma[i];
        float bt[KMAX + 1];
        for (int j = 0; j <= KMAX; ++j) bt[j] = beta[j];
        fcoef[0] = alpha[0];
        float gp = 1.0f;
        skipflag[0] = 0;
        for (int k = 1; k <= KMAX; ++k) {
            gp *= g[k - 1];
            fcoef[k] = bt[k] * gp;         // same rounding order as before
            float gl = 1.0f;
            for (int i = 0; i < k; ++i) gl *= fabsf(g[i]);
            float rem = 0.0f;
            for (int j = k; j <= KMAX; ++j) {
                rem = fmaxf(rem, fabsf(bt[j]) * gl);
                if (j < KMAX) gl *= fabsf(g[j - 1]);
            }
            skipflag[k] = (rem < SKIP_EPS) ? 1 : 0;
        }
        int L = 1;                          // skipflag is monotone 0 -> 1
        for (int k = 1; k <= KMAX; ++k) if (!skipflag[k]) L = k;
        meta[0] = L;
    }
}

// Chunk-aggregated binning: stash chunk in LDS, reserve one contiguous range
// per (block,bucket) with a single atomicAdd of the count, write dense runs.
__global__ __launch_bounds__(256) void bin_kernel(const int* __restrict__ row,
                                                  const int* __restrict__ col,
                                                  const int* __restrict__ seg_off,
                                                  int* __restrict__ cnt2,
                                                  int* __restrict__ bin) {
    __shared__ unsigned sval[CH];          // 32 KB packed (rl<<17 | c)
    __shared__ unsigned short sbuck[CH];   // 16 KB bucket ids
    __shared__ int lhist[NBUCK], lpos[NBUCK], lbase[NBUCK];
    int t = threadIdx.x;
    for (int b = t; b < NBUCK; b += 256) { lhist[b] = 0; lpos[b] = 0; }
    __syncthreads();
    int e0 = blockIdx.x * CH;
    int n = NE - e0; if (n > CH) n = CH;
    for (int i = t; i < n; i += 256) {
        int r = row[e0 + i], c = col[e0 + i];
        int b = r >> 7;
        sval[i] = ((unsigned)(r & 127) << 17) | (unsigned)c;
        sbuck[i] = (unsigned short)b;
        atomicAdd(&lhist[b], 1);
    }
    __syncthreads();
    int x = blockIdx.x & 7;
    for (int b = t; b < NBUCK; b += 256)
        if (lhist[b]) lbase[b] = seg_off[x * NBUCK + b] +
                                 atomicAdd(&cnt2[x * NBUCK + b], lhist[b]);
    __syncthreads();
    for (int i = t; i < n; i += 256) {
        int b = sbuck[i];
        int p = atomicAdd(&lpos[b], 1);
        bin[lbase[b] + p] = sval[i];
    }
}

// One block per bucket: count per-row degrees in LDS, 128-wide LDS scan of
// roundup8(deg) -> rowptr/degp/dis, then place edges (epk[].x = col) +
// row pad sentinels (col = NN -> zeroed table row, weight 0).
__global__ __launch_bounds__(256) void csr_fill_kernel(const int* __restrict__ bbase,
                                                       const int* __restrict__ ebase,
                                                       const int* __restrict__ bin,
                                                       i32x2* __restrict__ epk,
                                                       int* __restrict__ rowptr,
                                                       int* __restrict__ degp,
                                                       float* __restrict__ dis) {
    __shared__ int cnt[128], rb[128], sscan[128];
    int b = blockIdx.x, t = threadIdx.x;
    int r0 = b << 7;
    int nrows = NN - r0; if (nrows > 128) nrows = 128;
    if (t < 128) cnt[t] = 0;
    __syncthreads();
    int bb = bbase[b], be = bbase[b + 1];
    for (int i = bb + t; i < be; i += 256)
        atomicAdd(&cnt[((unsigned)bin[i]) >> 17], 1);
    __syncthreads();
    int d = 0, d8 = 0;
    if (t < 128) { d = cnt[t]; d8 = (d + 7) & ~7; sscan[t] = d8; }
    __syncthreads();
    for (int off = 1; off < 128; off <<= 1) {
        int v = 0;
        if (t < 128 && t >= off) v = sscan[t - off];
        __syncthreads();
        if (t < 128) sscan[t] += v;
        __syncthreads();
    }
    int eb0 = ebase[b];
    if (t < 128) {
        rb[t] = eb0 + sscan[t] - d8;       // row base (multiple of 8)
        if (t < nrows) {
            rowptr[r0 + t] = rb[t];
            degp[r0 + t] = d8;
            dis[r0 + t] = d > 0 ? rsqrtf((float)d) : 0.0f;
        }
        cnt[t] = 0;                        // reset for placement pass
    }
    __syncthreads();
    for (int i = bb + t; i < be; i += 256) {
        unsigned e = (unsigned)bin[i];
        int rl = e >> 17;
        int c = e & 0x1FFFF;
        int p = atomicAdd(&cnt[rl], 1);
        epk[rb[rl] + p].x = c;
    }
    __syncthreads();
    // row pad slots deg..roundup8(deg)-1 -> sentinel col NN (zero row, w=0)
    for (int i = t; i < nrows * 8; i += 256) {
        int rl = i >> 3, j = i & 7;
        int dd = cnt[rl];
        if (dd + j < ((dd + 7) & ~7)) epk[rb[rl] + dd + j].x = NN;
    }
}

// Finalize edge meta in place: epk[i] = { byte_offset = min(col,NN)<<7
// (128-B half-table rows), bits(weight = dis[min(col,NN)]) }.
__global__ __launch_bounds__(256) void emeta_kernel(i32x2* __restrict__ epk,
                                                    const float* __restrict__ dis) {
    int i = blockIdx.x * 256 + threadIdx.x;
    if (i >= NEPAD) return;
    unsigned c = (unsigned)epk[i].x;
    unsigned cc = c < NN ? c : NN;       // sentinel/garbage -> zero row NN
    i32x2 v;
    v.x = (int)(cc << 7);                // byte offset into bf16 HALF tables
    v.y = __float_as_int(dis[cc]);       // dis[NN] = 0
    epk[i] = v;
}

// x (fp32, [NN][128]) -> two bf16 half tables ([NN][64] each)
__global__ __launch_bounds__(256) void x2bf_kernel(const float4* __restrict__ x4,
                                                   u32x4* __restrict__ xlo,
                                                   u32x4* __restrict__ xhi) {
    int i = blockIdx.x * 256 + threadIdx.x;   // one u32x4 (8 bf16) per thread
    if (i >= ND / 8) return;
    int r = i >> 4;              // row
    int j = i & 15;              // 8-feature block 0..15
    float4 t0 = x4[i * 2];
    float4 t1 = x4[i * 2 + 1];
    u32x4 v;
    v.x = packbf(t0.x, t0.y); v.y = packbf(t0.z, t0.w);
    v.z = packbf(t1.x, t1.y); v.w = packbf(t1.z, t1.w);
    u32x4* dst = (j < 8) ? xlo : xhi;
    dst[r * 8 + (j & 7)] = v;
}

#define FMA8(U, W)                                               \
    a0 = fmaf(W, bflo(U.x), a0); a1 = fmaf(W, bfhi(U.x), a1);    \
    a2 = fmaf(W, bflo(U.y), a2); a3 = fmaf(W, bfhi(U.y), a3);    \
    a4 = fmaf(W, bflo(U.z), a4); a5 = fmaf(W, bfhi(U.z), a5);    \
    a6 = fmaf(W, bflo(U.w), a6); a7 = fmaf(W, bfhi(U.w), a7);

// Fused SpMV + Jacobi combine on ONE 64-feature half (12.8 MB gather table:
// halves per-XCD L2 oversubscription vs the 25.6 MB full table).
// 8 edge slots/wave (q=lane>>3), 8 feature-blocks (d=lane&7): each edge's
// 128-B half-row is read by 8 lanes x 16 B, fully coalesced.
__global__ __launch_bounds__(256) void spmv_row_kernel(
    const int* __restrict__ rowptr, const int* __restrict__ degp,
    const i32x2* __restrict__ epk, const float* __restrict__ dis,
    const unsigned short* __restrict__ yb, const unsigned short* __restrict__ p2b,
    const float* __restrict__ p2f, const float* __restrict__ xf,
    const int* __restrict__ skipflag, const float* __restrict__ fcoef,
    const int* __restrict__ meta, unsigned short* __restrict__ dstb,
    float* __restrict__ out, float v1, float v2, float v3, int k, int first,
    int fbase) {
    if (!first && skipflag[k]) return;   // this and all later terms negligible

    int r = blockIdx.x * RPB + (threadIdx.x >> 6);
    if (r >= NN) return;
    int lane = threadIdx.x & 63;
    int q = lane >> 3;          // edge slot within group of 8
    int d = lane & 7;           // uint4 slot: features 8d .. 8d+7 of the half
    const char* ybb = (const char*)yb + (d << 4);

    int jb = rowptr[r];
    int je = jb + degp[r];

    float a0 = 0.f, a1 = 0.f, a2 = 0.f, a3 = 0.f;
    float a4 = 0.f, a5 = 0.f, a6 = 0.f, a7 = 0.f;

    int i = jb;
    for (; i + 32 <= je; i += 32) {
        i32x2 m0 = __builtin_nontemporal_load(epk + i + q);
        i32x2 m1 = __builtin_nontemporal_load(epk + i + q + 8);
        i32x2 m2 = __builtin_nontemporal_load(epk + i + q + 16);
        i32x2 m3 = __builtin_nontemporal_load(epk + i + q + 24);
        u32x4 u0 = *(const u32x4*)(ybb + m0.x);
        u32x4 u1 = *(const u32x4*)(ybb + m1.x);
        u32x4 u2 = *(const u32x4*)(ybb + m2.x);
        u32x4 u3 = *(const u32x4*)(ybb + m3.x);
        float w0 = __int_as_float(m0.y);
        float w1 = __int_as_float(m1.y);
        float w2 = __int_as_float(m2.y);
        float w3 = __int_as_float(m3.y);
        FMA8(u0, w0); FMA8(u1, w1); FMA8(u2, w2); FMA8(u3, w3);
    }
    for (; i < je; i += 8) {      // 8-edge tail steps (degp is a multiple of 8)
        i32x2 m0 = __builtin_nontemporal_load(epk + i + q);
        u32x4 u0 = *(const u32x4*)(ybb + m0.x);
        float w0 = __int_as_float(m0.y);
        FMA8(u0, w0);
    }

    // reduce across the 8 edge slots (lane bits 3,4,5)
    a0 += __shfl_xor(a0, 8);  a1 += __shfl_xor(a1, 8);
    a2 += __shfl_xor(a2, 8);  a3 += __shfl_xor(a3, 8);
    a4 += __shfl_xor(a4, 8);  a5 += __shfl_xor(a5, 8);
    a6 += __shfl_xor(a6, 8);  a7 += __shfl_xor(a7, 8);
    a0 += __shfl_xor(a0, 16); a1 += __shfl_xor(a1, 16);
    a2 += __shfl_xor(a2, 16); a3 += __shfl_xor(a3, 16);
    a4 += __shfl_xor(a4, 16); a5 += __shfl_xor(a5, 16);
    a6 += __shfl_xor(a6, 16); a7 += __shfl_xor(a7, 16);
    a0 += __shfl_xor(a0, 32); a1 += __shfl_xor(a1, 32);
    a2 += __shfl_xor(a2, 32); a3 += __shfl_xor(a3, 32);
    a4 += __shfl_xor(a4, 32); a5 += __shfl_xor(a5, 32);
    a6 += __shfl_xor(a6, 32); a7 += __shfl_xor(a7, 32);

    if (q == 0) {
        float dr = dis[r];
        float S0 = dr * a0, S1 = dr * a1, S2 = dr * a2, S3 = dr * a3;
        float S4 = dr * a4, S5 = dr * a5, S6 = dr * a6, S7 = dr * a7;
        size_t offt = (size_t)r * HD + (size_t)d * 8;          // half tables
        size_t offo = (size_t)r * D + fbase + (size_t)d * 8;   // out / x

        int L = meta[0];
        bool defer = (L <= 3);
        bool last = (k == L);

        float p10 = 0.f, p11 = 0.f, p12 = 0.f, p13 = 0.f;
        float p14 = 0.f, p15 = 0.f, p16 = 0.f, p17 = 0.f;
        if ((v1 != 0.0f) || (defer && last && k >= 2)) {
            u32x4 up1 = *(const u32x4*)(yb + offt);   // aliases gather table
            p10 = bflo(up1.x); p11 = bfhi(up1.x);
            p12 = bflo(up1.y); p13 = bfhi(up1.y);
            p14 = bflo(up1.z); p15 = bfhi(up1.z);
            p16 = bflo(up1.w); p17 = bfhi(up1.w);
        }

        float p20 = 0.f, p21 = 0.f, p22 = 0.f, p23 = 0.f;
        float p24 = 0.f, p25 = 0.f, p26 = 0.f, p27 = 0.f;
        bool needp2 = (v3 != 0.0f) || (!defer && first) ||
                      (defer && last && k >= 3);
        if (needp2) {
            if (p2f) {
                f32x4 t0 = __builtin_nontemporal_load((const f32x4*)(p2f + offo));
                f32x4 t1 = __builtin_nontemporal_load((const f32x4*)(p2f + offo) + 1);
                p20 = t0.x; p21 = t0.y; p22 = t0.z; p23 = t0.w;
                p24 = t1.x; p25 = t1.y; p26 = t1.z; p27 = t1.w;
            } else {
                u32x4 up2 = __builtin_nontemporal_load((const u32x4*)(p2b + offt));
                p20 = bflo(up2.x); p21 = bfhi(up2.x);
                p22 = bflo(up2.y); p23 = bfhi(up2.y);
                p24 = bflo(up2.z); p25 = bfhi(up2.z);
                p26 = bflo(up2.w); p27 = bfhi(up2.w);
            }
        }

        float pk0 = v1 * p10 + v2 * S0 + v3 * p20;
        float pk1 = v1 * p11 + v2 * S1 + v3 * p21;
        float pk2 = v1 * p12 + v2 * S2 + v3 * p22;
        float pk3 = v1 * p13 + v2 * S3 + v3 * p23;
        float pk4 = v1 * p14 + v2 * S4 + v3 * p24;
        float pk5 = v1 * p15 + v2 * S5 + v3 * p25;
        float pk6 = v1 * p16 + v2 * S6 + v3 * p26;
        float pk7 = v1 * p17 + v2 * S7 + v3 * p27;

        if (defer && !last) {
            // P_k half only; out untouched (written once by k == L)
            u32x4 pkv;
            pkv.x = packbf(pk0, pk1);
            pkv.y = packbf(pk2, pk3);
            pkv.z = packbf(pk4, pk5);
            pkv.w = packbf(pk6, pk7);
            *(u32x4*)(dstb + offt) = pkv;
        } else if (defer) {
            // last live term: fold everything, single nt out write, no dstb
            float A0 = fcoef[0];
            float bk = fcoef[k];
            float fm1 = (k >= 2) ? fcoef[k - 1] : 0.0f;
            float fm2 = (k >= 3) ? fcoef[k - 2] : 0.0f;
            f32x4 x0 = __builtin_nontemporal_load((const f32x4*)(xf + offo));
            f32x4 x1 = __builtin_nontemporal_load((const f32x4*)(xf + offo) + 1);
            f32x4 o0, o1;
            o0[0] = A0 * x0[0] + bk * pk0 + fm1 * p10 + fm2 * p20;
            o0[1] = A0 * x0[1] + bk * pk1 + fm1 * p11 + fm2 * p21;
            o0[2] = A0 * x0[2] + bk * pk2 + fm1 * p12 + fm2 * p22;
            o0[3] = A0 * x0[3] + bk * pk3 + fm1 * p13 + fm2 * p23;
            o1[0] = A0 * x1[0] + bk * pk4 + fm1 * p14 + fm2 * p24;
            o1[1] = A0 * x1[1] + bk * pk5 + fm1 * p15 + fm2 * p25;
            o1[2] = A0 * x1[2] + bk * pk6 + fm1 * p16 + fm2 * p26;
            o1[3] = A0 * x1[3] + bk * pk7 + fm1 * p17 + fm2 * p27;
            __builtin_nontemporal_store(o0, (f32x4*)(out + offo));
            __builtin_nontemporal_store(o1, (f32x4*)(out + offo) + 1);
        } else {
            // incremental fallback (L >= 4), per half
            float bk = fcoef[k];
            f32x4 o0, o1;
            if (first) {
                float A0 = fcoef[0];
                o0[0] = A0 * p20 + bk * pk0; o0[1] = A0 * p21 + bk * pk1;
                o0[2] = A0 * p22 + bk * pk2; o0[3] = A0 * p23 + bk * pk3;
                o1[0] = A0 * p24 + bk * pk4; o1[1] = A0 * p25 + bk * pk5;
                o1[2] = A0 * p26 + bk * pk6; o1[3] = A0 * p27 + bk * pk7;
            } else {
                f32x4 va = __builtin_nontemporal_load((const f32x4*)(out + offo));
                f32x4 vb = __builtin_nontemporal_load((const f32x4*)(out + offo) + 1);
                o0[0] = va[0] + bk * pk0; o0[1] = va[1] + bk * pk1;
                o0[2] = va[2] + bk * pk2; o0[3] = va[3] + bk * pk3;
                o1[0] = vb[0] + bk * pk4; o1[1] = vb[1] + bk * pk5;
                o1[2] = vb[2] + bk * pk6; o1[3] = vb[3] + bk * pk7;
            }
            __builtin_nontemporal_store(o0, (f32x4*)(out + offo));
            __builtin_nontemporal_store(o1, (f32x4*)(out + offo) + 1);
            u32x4 pkv;
            pkv.x = packbf(pk0, pk1);
            pkv.y = packbf(pk2, pk3);
            pkv.z = packbf(pk4, pk5);
            pkv.w = packbf(pk6, pk7);
            *(u32x4*)(dstb + offt) = pkv;
        }
    }
}

extern "C" void kernel_launch(void* const* d_in, const int* in_sizes, int n_in,
                              void* d_out, int out_size, void* d_ws, size_t ws_size,
                              hipStream_t stream) {
    const float* x = (const float*)d_in[0];
    const float* alpha = (const float*)d_in[1];
    const float* beta = (const float*)d_in[2];
    const float* gamma = (const float*)d_in[3];
    const int* edge = (const int*)d_in[4];
    const int* row = edge;        // edge_index[0]
    const int* col = edge + NE;   // edge_index[1]
    float* out = (float*)d_out;

    // workspace: six 64-feature half tables (12.8 MB each), each with a
    // trailing zero row at index NN (sentinel gathers).
    unsigned short* Xh[2];
    unsigned short* PAh[2];
    unsigned short* PBh[2];
    Xh[0] = (unsigned short*)d_ws;                 // NDPH
    Xh[1] = Xh[0] + NDPH;
    PAh[0] = Xh[1] + NDPH;
    PAh[1] = PAh[0] + NDPH;
    PBh[0] = PAh[1] + NDPH;
    PBh[1] = PBh[0] + NDPH;
    i32x2* epk = (i32x2*)(PBh[1] + NDPH);          // NEPAD {off,wbits}
    int* rowptr = (int*)(epk + NEPAD);             // NN
    int* degp = rowptr + NN;                       // NN (padded degree)
    float* dis = (float*)(degp + NN);              // NN+1 (sentinel)
    int* hist = (int*)(dis + NN + 1);              // 8*NBUCK
    int* cnt2 = hist + 8 * NBUCK;                  // 8*NBUCK
    int* seg_off = cnt2 + 8 * NBUCK;               // 8*NBUCK
    int* bbase = seg_off + 8 * NBUCK;              // NBUCK+1
    int* ebase = bbase + NBUCK + 1;                // NBUCK+1
    int* skipflag = ebase + NBUCK + 1;             // KMAX+1
    float* fcoef = (float*)(skipflag + KMAX + 1);  // KMAX+1
    int* meta = (int*)(fcoef + KMAX + 1);          // 1 (last live k)
    // bin buffer aliases d_out (12.8MB < 51.2MB; out fully rewritten by the
    // last live spmv afterwards, which never reads out)
    int* bin = (int*)d_out;

    // recurrence constants (a = b = 0.5, lmax = 2.0 -> tl = 1)
    const double a = 0.5, b = 0.5, tl = 1.0;
    const double c1 = (a - b) / 2.0, c2 = (a + b + 2.0) / 2.0;
    float u1 = (float)(c1 + c2 * (tl - 1.0));   // = 0
    float u2 = (float)(-c2 * tl);               // = -1.5

    const int XB = (ND / 8 + 255) / 256;
    const int WB = (NEPAD + 255) / 256;

    // ---- padded CSR build (LDS-aggregated, no per-edge global atomics) ----
    hipMemsetAsync(hist, 0, 8 * NBUCK * sizeof(int), stream);
    for (int h = 0; h < 2; ++h) {
        hipMemsetAsync(Xh[h] + NN * HD, 0, HD * sizeof(unsigned short), stream);
        hipMemsetAsync(PAh[h] + NN * HD, 0, HD * sizeof(unsigned short), stream);
        hipMemsetAsync(PBh[h] + NN * HD, 0, HD * sizeof(unsigned short), stream);
    }
    hist_kernel<<<NCB, 256, 0, stream>>>(row, hist);
    scan_small_kernel<<<1, 1024, 0, stream>>>(hist, seg_off, cnt2, bbase, ebase,
                                              alpha, beta, gamma, skipflag, fcoef,
                                              meta, dis);
    bin_kernel<<<NCB, 256, 0, stream>>>(row, col, seg_off, cnt2, bin);
    csr_fill_kernel<<<NBUCK, 256, 0, stream>>>(bbase, ebase, bin, epk,
                                               rowptr, degp, dis);
    emeta_kernel<<<WB, 256, 0, stream>>>(epk, dis);
    x2bf_kernel<<<XB, 256, 0, stream>>>((const float4*)x,
                                        (u32x4*)Xh[0], (u32x4*)Xh[1]);

    // ---- k = 1: P1 = -1.5*S(x), per half ----
    for (int h = 0; h < 2; ++h)
        spmv_row_kernel<<<RBLK, 256, 0, stream>>>(rowptr, degp, epk, dis, Xh[h],
                                                  nullptr, x, x, skipflag, fcoef,
                                                  meta, PAh[h], out,
                                                  u1, u2, 0.0f, 1, 1, h * HD);

    // ---- k = 2..10, per half (device-side truncation skips dead k;
    //      dispatch k == last-live folds the full output sum) ----
    for (int k = 2; k <= KMAX; ++k) {
        double dk = (double)k;
        double theta = (2 * dk + a + b) * (2 * dk + a + b - 1) / (2 * dk * (dk + a + b));
        double theta_p = (2 * dk + a + b - 1) * (a * a - b * b) /
                         (2 * dk * (dk + a + b) * (2 * dk + a + b - 2));
        double theta_pp = (dk + a - 1) * (dk + b - 1) * (2 * dk + a + b) /
                          (dk * (dk + a + b) * (2 * dk + a + b - 2));
        float v1 = (float)(theta * (tl - 1.0) + theta_p);
        float v2 = (float)(-theta * tl);
        float v3 = (float)(-theta_pp);

        for (int h = 0; h < 2; ++h) {
            unsigned short* p1 = (k % 2 == 0) ? PAh[h] : PBh[h];   // P_{k-1}
            unsigned short* dst = (k % 2 == 0) ? PBh[h] : PAh[h];  // P_{k-2} slot
            const unsigned short* p2b = (k == 2) ? Xh[h] : dst;
            spmv_row_kernel<<<RBLK, 256, 0, stream>>>(rowptr, degp, epk, dis,
                                                      p1, p2b, nullptr, x,
                                                      skipflag, fcoef, meta,
                                                      dst, out, v1, v2, v3,
                                                      k, 0, h * HD);
        }
    }
}

// Round 10
// 485.933 us; speedup vs baseline: 1.2182x; 1.2182x over previous
//
#include <hip/hip_runtime.h>

#define NN 100000
#define NE 3200000
#define D 128
#define ND (NN * D)
#define KMAX 10
#define RPB 4                         // rows (waves) per block
#define RBLK ((NN + RPB - 1) / RPB)   // 25000
#define NEPAD (NE + 8 * NN + 128)     // >= sum of padded bucket regions + slack
#define SKIP_EPS 1e-3f                // remaining-contribution cutoff
#define NBUCK ((NN + 127) / 128)      // 782 row-buckets of 128 rows
#define CH 8192                       // edges per chunk (hist/bin blocks)
#define NCB ((NE + CH - 1) / CH)      // 391 chunk blocks

typedef float f32x4 __attribute__((ext_vector_type(4)));

__device__ __forceinline__ float bflo(unsigned u) { return __uint_as_float(u << 16); }
__device__ __forceinline__ float bfhi(unsigned u) { return __uint_as_float(u & 0xffff0000u); }
__device__ __forceinline__ unsigned packbf(float lo, float hi) {
    unsigned bx = __float_as_uint(lo);
    bx = (bx + 0x7fffu + ((bx >> 16) & 1u)) >> 16;
    unsigned by = __float_as_uint(hi);
    by = (by + 0x7fffu + ((by >> 16) & 1u)) & 0xffff0000u;
    return by | bx;
}

// Per-chunk LDS histogram of bucket counts; flush with <=782 atomics/block.
__global__ __launch_bounds__(256) void hist_kernel(const int* __restrict__ row,
                                                   int* __restrict__ hist) {
    __shared__ int lh[NBUCK];
    int t = threadIdx.x;
    for (int b = t; b < NBUCK; b += 256) lh[b] = 0;
    __syncthreads();
    int e0 = blockIdx.x * CH;
    int n = NE - e0; if (n > CH) n = CH;
    for (int i = t; i < n; i += 256)
        atomicAdd(&lh[row[e0 + i] >> 7], 1);
    __syncthreads();
    int x = blockIdx.x & 7;
    for (int b = t; b < NBUCK; b += 256)
        if (lh[b]) atomicAdd(&hist[x * NBUCK + b], lh[b]);
}

// Single-block scans over buckets: bin layout (dense) + ecol regions (padded
// upper bound total+896, rounded to 8). Also fused coefficient/truncation
// precompute (incl. last-live-k -> meta[0]) and the dis sentinel.
__global__ __launch_bounds__(1024) void scan_small_kernel(
    const int* __restrict__ hist, int* __restrict__ seg_off,
    int* __restrict__ cnt2, int* __restrict__ bbase, int* __restrict__ ebase,
    const float* __restrict__ alpha, const float* __restrict__ beta,
    const float* __restrict__ gamma, int* __restrict__ skipflag,
    float* __restrict__ fcoef, int* __restrict__ meta,
    float* __restrict__ dis) {
    __shared__ int sA[1024], sB[1024];
    int t = threadIdx.x;
    int tot = 0;
    int so[8];
    if (t < NBUCK) {
        int s = 0;
        for (int x = 0; x < 8; ++x) { so[x] = s; s += hist[x * NBUCK + t]; }
        tot = s;
    }
    int reg = (t < NBUCK) ? ((tot + 896 + 7) & ~7) : 0;
    sA[t] = tot; sB[t] = reg;
    __syncthreads();
    for (int off = 1; off < 1024; off <<= 1) {
        int a = (t >= off) ? sA[t - off] : 0;
        int c = (t >= off) ? sB[t - off] : 0;
        __syncthreads();
        sA[t] += a; sB[t] += c;
        __syncthreads();
    }
    if (t < NBUCK) {
        int ba = sA[t] - tot, eb = sB[t] - reg;
        bbase[t] = ba; ebase[t] = eb;
        for (int x = 0; x < 8; ++x) {
            seg_off[x * NBUCK + t] = ba + so[x];
            cnt2[x * NBUCK + t] = 0;
        }
    }
    if (t == 0) {
        bbase[NBUCK] = sA[1023];
        ebase[NBUCK] = sB[1023];
        dis[NN] = 0.0f;                    // sentinel weight
        float g[KMAX];
        for (int i = 0; i < KMAX; ++i) g[i] = gamma[i];
        float bt[KMAX + 1];
        for (int j = 0; j <= KMAX; ++j) bt[j] = beta[j];
        fcoef[0] = alpha[0];
        float gp = 1.0f;
        skipflag[0] = 0;
        for (int k = 1; k <= KMAX; ++k) {
            gp *= g[k - 1];
            fcoef[k] = bt[k] * gp;         // same rounding order as before
            float gl = 1.0f;
            for (int i = 0; i < k; ++i) gl *= fabsf(g[i]);
            float rem = 0.0f;
            for (int j = k; j <= KMAX; ++j) {
                rem = fmaxf(rem, fabsf(bt[j]) * gl);
                if (j < KMAX) gl *= fabsf(g[j - 1]);
            }
            skipflag[k] = (rem < SKIP_EPS) ? 1 : 0;
        }
        int L = 1;                          // skipflag is monotone 0 -> 1
        for (int k = 1; k <= KMAX; ++k) if (!skipflag[k]) L = k;
        meta[0] = L;
    }
}

// Chunk-aggregated binning: stash chunk in LDS, reserve one contiguous range
// per (block,bucket) with a single atomicAdd of the count, write dense runs.
__global__ __launch_bounds__(256) void bin_kernel(const int* __restrict__ row,
                                                  const int* __restrict__ col,
                                                  const int* __restrict__ seg_off,
                                                  int* __restrict__ cnt2,
                                                  int* __restrict__ bin) {
    __shared__ unsigned sval[CH];          // 32 KB packed (rl<<17 | c)
    __shared__ unsigned short sbuck[CH];   // 16 KB bucket ids
    __shared__ int lhist[NBUCK], lpos[NBUCK], lbase[NBUCK];
    int t = threadIdx.x;
    for (int b = t; b < NBUCK; b += 256) { lhist[b] = 0; lpos[b] = 0; }
    __syncthreads();
    int e0 = blockIdx.x * CH;
    int n = NE - e0; if (n > CH) n = CH;
    for (int i = t; i < n; i += 256) {
        int r = row[e0 + i], c = col[e0 + i];
        int b = r >> 7;
        sval[i] = ((unsigned)(r & 127) << 17) | (unsigned)c;
        sbuck[i] = (unsigned short)b;
        atomicAdd(&lhist[b], 1);
    }
    __syncthreads();
    int x = blockIdx.x & 7;
    for (int b = t; b < NBUCK; b += 256)
        if (lhist[b]) lbase[b] = seg_off[x * NBUCK + b] +
                                 atomicAdd(&cnt2[x * NBUCK + b], lhist[b]);
    __syncthreads();
    for (int i = t; i < n; i += 256) {
        int b = sbuck[i];
        int p = atomicAdd(&lpos[b], 1);
        bin[lbase[b] + p] = sval[i];
    }
}

// One block per bucket: count per-row degrees in LDS, 128-wide LDS scan of
// roundup8(deg) -> rowptr/degp/dis, then place edges + row pad sentinels.
// (Gap/tail slots are never read: spmv stops at rowptr[r]+degp[r].)
__global__ __launch_bounds__(256) void csr_fill_kernel(const int* __restrict__ bbase,
                                                       const int* __restrict__ ebase,
                                                       const int* __restrict__ bin,
                                                       int* __restrict__ ecol,
                                                       int* __restrict__ rowptr,
                                                       int* __restrict__ degp,
                                                       float* __restrict__ dis) {
    __shared__ int cnt[128], rb[128], sscan[128];
    int b = blockIdx.x, t = threadIdx.x;
    int r0 = b << 7;
    int nrows = NN - r0; if (nrows > 128) nrows = 128;
    if (t < 128) cnt[t] = 0;
    __syncthreads();
    int bb = bbase[b], be = bbase[b + 1];
    for (int i = bb + t; i < be; i += 256)
        atomicAdd(&cnt[((unsigned)bin[i]) >> 17], 1);
    __syncthreads();
    int d = 0, d8 = 0;
    if (t < 128) { d = cnt[t]; d8 = (d + 7) & ~7; sscan[t] = d8; }
    __syncthreads();
    for (int off = 1; off < 128; off <<= 1) {
        int v = 0;
        if (t < 128 && t >= off) v = sscan[t - off];
        __syncthreads();
        if (t < 128) sscan[t] += v;
        __syncthreads();
    }
    int eb0 = ebase[b];
    if (t < 128) {
        rb[t] = eb0 + sscan[t] - d8;       // row base (multiple of 8)
        if (t < nrows) {
            rowptr[r0 + t] = rb[t];
            degp[r0 + t] = d8;
            dis[r0 + t] = d > 0 ? rsqrtf((float)d) : 0.0f;
        }
        cnt[t] = 0;                        // reset for placement pass
    }
    __syncthreads();
    for (int i = bb + t; i < be; i += 256) {
        unsigned e = (unsigned)bin[i];
        int rl = e >> 17;
        int c = e & 0x1FFFF;
        int p = atomicAdd(&cnt[rl], 1);
        ecol[rb[rl] + p] = c;
    }
    __syncthreads();
    // row pad slots deg..roundup8(deg)-1 -> sentinel (read by spmv, must be w=0)
    for (int i = t; i < nrows * 8; i += 256) {
        int rl = i >> 3, j = i & 7;
        int dd = cnt[rl];
        if (dd + j < ((dd + 7) & ~7)) ecol[rb[rl] + dd + j] = NN;
    }
}

// Fused finalize: (a) edge meta -> { ewt[e]=dis[col] (0 for sentinel/garbage),
// ecol[e]=clamped col<<8 byte offset }; (b) x fp32 -> bf16 (RNE).
// One launch instead of two (independent elementwise ranges).
__global__ __launch_bounds__(256) void finalize_kernel(int* __restrict__ ecol,
                                                       const float* __restrict__ dis,
                                                       float* __restrict__ ewt,
                                                       const float2* __restrict__ x2,
                                                       unsigned* __restrict__ xb) {
    int i = blockIdx.x * 256 + threadIdx.x;
    if (i < NEPAD) {
        unsigned c = (unsigned)ecol[i];
        unsigned cc = c < NN ? c : NN;       // sentinel/garbage -> NN (dis[NN]=0)
        ewt[i] = dis[cc];
        ecol[i] = (int)((c < NN ? c : 0u) << 8);   // byte offset into bf16 rows
    } else {
        int j = i - NEPAD;
        if (j < ND / 2) {
            float2 v = x2[j];
            xb[j] = packbf(v.x, v.y);
        }
    }
}

#define FMA8(U, W)                                               \
    a0 = fmaf(W, bflo(U.x), a0); a1 = fmaf(W, bfhi(U.x), a1);    \
    a2 = fmaf(W, bflo(U.y), a2); a3 = fmaf(W, bfhi(U.y), a3);    \
    a4 = fmaf(W, bflo(U.z), a4); a5 = fmaf(W, bfhi(U.z), a5);    \
    a6 = fmaf(W, bflo(U.w), a6); a7 = fmaf(W, bfhi(U.w), a7);

// Fused SpMV + Jacobi combine. One wave per row, quad q handles edges
// q, q+4, q+8, ... Deferred-output mode when last live term L <= 3:
// k<L writes only P_k (bf16); k==L writes out = a0*x + sum f_j*P_j in one
// pass. Incremental fallback for L >= 4. out stores are non-temporal (sink).
__global__ __launch_bounds__(256) void spmv_row_kernel(
    const int* __restrict__ rowptr, const int* __restrict__ degp,
    const int* __restrict__ ecol, const float* __restrict__ ewt,
    const float* __restrict__ dis,
    const unsigned short* __restrict__ yb, const unsigned short* __restrict__ p2b,
    const float* __restrict__ p2f, const float* __restrict__ xf,
    const int* __restrict__ skipflag, const float* __restrict__ fcoef,
    const int* __restrict__ meta, unsigned short* __restrict__ dstb,
    float* __restrict__ out, float v1, float v2, float v3, int k, int first) {
    if (!first && skipflag[k]) return;   // this and all later terms negligible

    int r = blockIdx.x * RPB + (threadIdx.x >> 6);
    if (r >= NN) return;
    int lane = threadIdx.x & 63;
    int q = lane >> 4;          // edge slot within group of 4
    int d = lane & 15;          // uint4 slot: features 8d .. 8d+7
    const char* ybb = (const char*)yb + (d << 4);

    int jb = rowptr[r];
    int je = jb + degp[r];

    float a0 = 0.f, a1 = 0.f, a2 = 0.f, a3 = 0.f;
    float a4 = 0.f, a5 = 0.f, a6 = 0.f, a7 = 0.f;

    int i = jb;
    for (; i + 16 <= je; i += 16) {
        int e0 = ecol[i + q];       float w0 = ewt[i + q];
        int e1 = ecol[i + q + 4];   float w1 = ewt[i + q + 4];
        int e2 = ecol[i + q + 8];   float w2 = ewt[i + q + 8];
        int e3 = ecol[i + q + 12];  float w3 = ewt[i + q + 12];
        uint4 u0 = *(const uint4*)(ybb + e0);
        uint4 u1 = *(const uint4*)(ybb + e1);
        uint4 u2 = *(const uint4*)(ybb + e2);
        uint4 u3 = *(const uint4*)(ybb + e3);
        FMA8(u0, w0); FMA8(u1, w1); FMA8(u2, w2); FMA8(u3, w3);
    }
    if (i < je) {                 // 8-edge tail (degp is a multiple of 8)
        int e0 = ecol[i + q];      float w0 = ewt[i + q];
        int e1 = ecol[i + q + 4];  float w1 = ewt[i + q + 4];
        uint4 u0 = *(const uint4*)(ybb + e0);
        uint4 u1 = *(const uint4*)(ybb + e1);
        FMA8(u0, w0); FMA8(u1, w1);
    }

    // reduce across the 4 edge slots (lane bits 4,5)
    a0 += __shfl_xor(a0, 16); a1 += __shfl_xor(a1, 16);
    a2 += __shfl_xor(a2, 16); a3 += __shfl_xor(a3, 16);
    a4 += __shfl_xor(a4, 16); a5 += __shfl_xor(a5, 16);
    a6 += __shfl_xor(a6, 16); a7 += __shfl_xor(a7, 16);
    a0 += __shfl_xor(a0, 32); a1 += __shfl_xor(a1, 32);
    a2 += __shfl_xor(a2, 32); a3 += __shfl_xor(a3, 32);
    a4 += __shfl_xor(a4, 32); a5 += __shfl_xor(a5, 32);
    a6 += __shfl_xor(a6, 32); a7 += __shfl_xor(a7, 32);

    if (q == 0) {
        float dr = dis[r];
        float S0 = dr * a0, S1 = dr * a1, S2 = dr * a2, S3 = dr * a3;
        float S4 = dr * a4, S5 = dr * a5, S6 = dr * a6, S7 = dr * a7;
        size_t off = (size_t)r * D + (size_t)d * 8;

        int L = meta[0];
        bool defer = (L <= 3);
        bool last = (k == L);

        float p10 = 0.f, p11 = 0.f, p12 = 0.f, p13 = 0.f;
        float p14 = 0.f, p15 = 0.f, p16 = 0.f, p17 = 0.f;
        if ((v1 != 0.0f) || (defer && last && k >= 2)) {
            uint4 up1 = *(const uint4*)(yb + off);
            p10 = bflo(up1.x); p11 = bfhi(up1.x);
            p12 = bflo(up1.y); p13 = bfhi(up1.y);
            p14 = bflo(up1.z); p15 = bfhi(up1.z);
            p16 = bflo(up1.w); p17 = bfhi(up1.w);
        }

        float p20 = 0.f, p21 = 0.f, p22 = 0.f, p23 = 0.f;
        float p24 = 0.f, p25 = 0.f, p26 = 0.f, p27 = 0.f;
        bool needp2 = (v3 != 0.0f) || (!defer && first) ||
                      (defer && last && k >= 3);
        if (needp2) {
            if (p2f) {
                float4 t0 = *(const float4*)(p2f + off);
                float4 t1 = *(const float4*)(p2f + off + 4);
                p20 = t0.x; p21 = t0.y; p22 = t0.z; p23 = t0.w;
                p24 = t1.x; p25 = t1.y; p26 = t1.z; p27 = t1.w;
            } else {
                uint4 up2 = *(const uint4*)(p2b + off);
                p20 = bflo(up2.x); p21 = bfhi(up2.x);
                p22 = bflo(up2.y); p23 = bfhi(up2.y);
                p24 = bflo(up2.z); p25 = bfhi(up2.z);
                p26 = bflo(up2.w); p27 = bfhi(up2.w);
            }
        }

        float pk0 = v1 * p10 + v2 * S0 + v3 * p20;
        float pk1 = v1 * p11 + v2 * S1 + v3 * p21;
        float pk2 = v1 * p12 + v2 * S2 + v3 * p22;
        float pk3 = v1 * p13 + v2 * S3 + v3 * p23;
        float pk4 = v1 * p14 + v2 * S4 + v3 * p24;
        float pk5 = v1 * p15 + v2 * S5 + v3 * p25;
        float pk6 = v1 * p16 + v2 * S6 + v3 * p26;
        float pk7 = v1 * p17 + v2 * S7 + v3 * p27;

        if (defer && !last) {
            // P_k only; out untouched (written once by k == L)
            uint4 pkv;
            pkv.x = packbf(pk0, pk1);
            pkv.y = packbf(pk2, pk3);
            pkv.z = packbf(pk4, pk5);
            pkv.w = packbf(pk6, pk7);
            *(uint4*)(dstb + off) = pkv;
        } else if (defer) {
            // last live term: fold everything, single nt out write, no dstb
            float A0 = fcoef[0];
            float bk = fcoef[k];
            float fm1 = (k >= 2) ? fcoef[k - 1] : 0.0f;
            float fm2 = (k >= 3) ? fcoef[k - 2] : 0.0f;
            f32x4 x0 = *(const f32x4*)(xf + off);
            f32x4 x1 = *(const f32x4*)(xf + off + 4);
            f32x4 o0, o1;
            o0[0] = A0 * x0[0] + bk * pk0 + fm1 * p10 + fm2 * p20;
            o0[1] = A0 * x0[1] + bk * pk1 + fm1 * p11 + fm2 * p21;
            o0[2] = A0 * x0[2] + bk * pk2 + fm1 * p12 + fm2 * p22;
            o0[3] = A0 * x0[3] + bk * pk3 + fm1 * p13 + fm2 * p23;
            o1[0] = A0 * x1[0] + bk * pk4 + fm1 * p14 + fm2 * p24;
            o1[1] = A0 * x1[1] + bk * pk5 + fm1 * p15 + fm2 * p25;
            o1[2] = A0 * x1[2] + bk * pk6 + fm1 * p16 + fm2 * p26;
            o1[3] = A0 * x1[3] + bk * pk7 + fm1 * p17 + fm2 * p27;
            __builtin_nontemporal_store(o0, (f32x4*)(out + off));
            __builtin_nontemporal_store(o1, (f32x4*)(out + off) + 1);
        } else {
            // incremental fallback (L >= 4): original behavior
            float bk = fcoef[k];
            f32x4 o0, o1;
            if (first) {
                float A0 = fcoef[0];
                o0[0] = A0 * p20 + bk * pk0; o0[1] = A0 * p21 + bk * pk1;
                o0[2] = A0 * p22 + bk * pk2; o0[3] = A0 * p23 + bk * pk3;
                o1[0] = A0 * p24 + bk * pk4; o1[1] = A0 * p25 + bk * pk5;
                o1[2] = A0 * p26 + bk * pk6; o1[3] = A0 * p27 + bk * pk7;
            } else {
                f32x4 va = __builtin_nontemporal_load((const f32x4*)(out + off));
                f32x4 vb = __builtin_nontemporal_load((const f32x4*)(out + off) + 1);
                o0[0] = va[0] + bk * pk0; o0[1] = va[1] + bk * pk1;
                o0[2] = va[2] + bk * pk2; o0[3] = va[3] + bk * pk3;
                o1[0] = vb[0] + bk * pk4; o1[1] = vb[1] + bk * pk5;
                o1[2] = vb[2] + bk * pk6; o1[3] = vb[3] + bk * pk7;
            }
            __builtin_nontemporal_store(o0, (f32x4*)(out + off));
            __builtin_nontemporal_store(o1, (f32x4*)(out + off) + 1);
            uint4 pkv;
            pkv.x = packbf(pk0, pk1);
            pkv.y = packbf(pk2, pk3);
            pkv.z = packbf(pk4, pk5);
            pkv.w = packbf(pk6, pk7);
            *(uint4*)(dstb + off) = pkv;
        }
    }
}

extern "C" void kernel_launch(void* const* d_in, const int* in_sizes, int n_in,
                              void* d_out, int out_size, void* d_ws, size_t ws_size,
                              hipStream_t stream) {
    const float* x = (const float*)d_in[0];
    const float* alpha = (const float*)d_in[1];
    const float* beta = (const float*)d_in[2];
    const float* gamma = (const float*)d_in[3];
    const int* edge = (const int*)d_in[4];
    const int* row = edge;        // edge_index[0]
    const int* col = edge + NE;   // edge_index[1]
    float* out = (float*)d_out;

    // workspace layout (Xb at d_ws start -> 256-B row alignment for uint4)
    unsigned short* Xb = (unsigned short*)d_ws;    // ND bf16
    unsigned short* PA = Xb + ND;                  // ND bf16
    unsigned short* PB = PA + ND;                  // ND bf16
    int* ecol = (int*)(PB + ND);                   // NEPAD (later: col<<8)
    float* ewt = (float*)(ecol + NEPAD);           // NEPAD edge weights
    int* rowptr = (int*)(ewt + NEPAD);             // NN
    int* degp = rowptr + NN;                       // NN (padded degree)
    float* dis = (float*)(degp + NN);              // NN+1 (sentinel)
    int* hist = (int*)(dis + NN + 1);              // 8*NBUCK
    int* cnt2 = hist + 8 * NBUCK;                  // 8*NBUCK
    int* seg_off = cnt2 + 8 * NBUCK;               // 8*NBUCK
    int* bbase = seg_off + 8 * NBUCK;              // NBUCK+1
    int* ebase = bbase + NBUCK + 1;                // NBUCK+1
    int* skipflag = ebase + NBUCK + 1;             // KMAX+1
    float* fcoef = (float*)(skipflag + KMAX + 1);  // KMAX+1
    int* meta = (int*)(fcoef + KMAX + 1);          // 1 (last live k)
    // bin buffer aliases d_out (12.8MB < 51.2MB; out fully rewritten by the
    // last live spmv afterwards, which never reads out)
    int* bin = (int*)d_out;

    // recurrence constants (a = b = 0.5, lmax = 2.0 -> tl = 1)
    const double a = 0.5, b = 0.5, tl = 1.0;
    const double c1 = (a - b) / 2.0, c2 = (a + b + 2.0) / 2.0;
    float u1 = (float)(c1 + c2 * (tl - 1.0));   // = 0
    float u2 = (float)(-c2 * tl);               // = -1.5

    const int FB = (NEPAD + ND / 2 + 255) / 256;

    // ---- padded CSR build (LDS-aggregated, no per-edge global atomics) ----
    hipMemsetAsync(hist, 0, 8 * NBUCK * sizeof(int), stream);
    hist_kernel<<<NCB, 256, 0, stream>>>(row, hist);
    scan_small_kernel<<<1, 1024, 0, stream>>>(hist, seg_off, cnt2, bbase, ebase,
                                              alpha, beta, gamma, skipflag, fcoef,
                                              meta, dis);
    bin_kernel<<<NCB, 256, 0, stream>>>(row, col, seg_off, cnt2, bin);
    csr_fill_kernel<<<NBUCK, 256, 0, stream>>>(bbase, ebase, bin, ecol,
                                               rowptr, degp, dis);
    finalize_kernel<<<FB, 256, 0, stream>>>(ecol, dis, ewt,
                                            (const float2*)x, (unsigned*)Xb);

    // ---- k = 1: P1 = -1.5*S(x) ----
    spmv_row_kernel<<<RBLK, 256, 0, stream>>>(rowptr, degp, ecol, ewt, dis, Xb,
                                              nullptr, x, x, skipflag, fcoef,
                                              meta, PA, out, u1, u2, 0.0f, 1, 1);

    // ---- k = 2..10 (device-side adaptive truncation skips negligible k;
    //      dispatch k == last-live folds the full output sum) ----
    for (int k = 2; k <= KMAX; ++k) {
        double dk = (double)k;
        double theta = (2 * dk + a + b) * (2 * dk + a + b - 1) / (2 * dk * (dk + a + b));
        double theta_p = (2 * dk + a + b - 1) * (a * a - b * b) /
                         (2 * dk * (dk + a + b) * (2 * dk + a + b - 2));
        double theta_pp = (dk + a - 1) * (dk + b - 1) * (2 * dk + a + b) /
                          (dk * (dk + a + b) * (2 * dk + a + b - 2));
        float v1 = (float)(theta * (tl - 1.0) + theta_p);
        float v2 = (float)(-theta * tl);
        float v3 = (float)(-theta_pp);

        unsigned short* p1 = (k % 2 == 0) ? PA : PB;   // P_{k-1}
        unsigned short* dst = (k % 2 == 0) ? PB : PA;  // slot of P_{k-2}
        const unsigned short* p2b = dst;               // read before overwrite
        const float* p2f = (k == 2) ? x : nullptr;     // fp32 x at k=2

        spmv_row_kernel<<<RBLK, 256, 0, stream>>>(rowptr, degp, ecol, ewt, dis,
                                                  p1, p2b, p2f, x, skipflag,
                                                  fcoef, meta, dst, out,
                                                  v1, v2, v3, k, 0);
    }
}